// Round 1
// baseline (226.758 us; speedup 1.0000x reference)
//
#include <hip/hip_runtime.h>
#include <hip/hip_bf16.h>
#include <stdint.h>

#define BATCH 256
#define TSLOT 27
#define NTOT  (BATCH * TSLOT)   // 6912
#define DIM   1024
#define BM    128
#define BK    64
#define NTILES (NTOT / BM)      // 54
#define KSTEPS (DIM / BK)       // 16

typedef __attribute__((ext_vector_type(8))) short short8;
typedef __attribute__((ext_vector_type(4))) float f32x4;

// ---------- prep: effective labels, -1 for invalid (padded) slots ----------
__global__ void prep_kernel(const int* __restrict__ tgt, int* __restrict__ elab) {
    int b = threadIdx.x;
    if (b >= BATCH) return;
    const int* t = tgt + b * TSLOT;
    int fz = 1;  // argmax over all-False -> 0, +1 => 1
    for (int i = 1; i < TSLOT; ++i) {
        if (t[i] == 0) { fz = i; break; }
    }
    int* e = elab + b * TSLOT;
    for (int i = 0; i < TSLOT; ++i) e[i] = (i < fz) ? t[i] : -1;
}

// ---------- zero scratch accumulators ----------
__global__ void zero_kernel(float* __restrict__ p, int n) {
    int i = blockIdx.x * blockDim.x + threadIdx.x;
    if (i < n) p[i] = 0.0f;
}

// ---------- row L2-normalize f32 -> bf16 ----------
__global__ __launch_bounds__(256) void norm_kernel(const float* __restrict__ in,
                                                   __hip_bfloat16* __restrict__ out) {
    int row = blockIdx.x;
    int tid = threadIdx.x;
    const float4 v = *(const float4*)(in + (size_t)row * DIM + tid * 4);
    float ss = v.x * v.x + v.y * v.y + v.z * v.z + v.w * v.w;
    #pragma unroll
    for (int off = 1; off < 64; off <<= 1) ss += __shfl_xor(ss, off);
    __shared__ float wsum[4];
    int lane = tid & 63, w = tid >> 6;
    if (lane == 0) wsum[w] = ss;
    __syncthreads();
    float tot = wsum[0] + wsum[1] + wsum[2] + wsum[3];
    float scale = 1.0f / fmaxf(sqrtf(tot), 1e-12f);
    __hip_bfloat16 h0 = __float2bfloat16(v.x * scale);
    __hip_bfloat16 h1 = __float2bfloat16(v.y * scale);
    __hip_bfloat16 h2 = __float2bfloat16(v.z * scale);
    __hip_bfloat16 h3 = __float2bfloat16(v.w * scale);
    ushort4 o;
    o.x = *(unsigned short*)&h0;
    o.y = *(unsigned short*)&h1;
    o.z = *(unsigned short*)&h2;
    o.w = *(unsigned short*)&h3;
    *(ushort4*)((unsigned short*)out + (size_t)row * DIM + tid * 4) = o;
}

// ---------- fused GEMM (f @ f^T) + masked exp accumulation ----------
// 128x128 tile, BK=64, 4 waves (2x2), 16x16x32 bf16 MFMA.
// LDS: linear dest for global_load_lds; XOR swizzle byte^((row&7)<<4) applied
// to the GLOBAL source address and to the ds_read address (involution).
__global__ __launch_bounds__(256) void gemm_kernel(const __hip_bfloat16* __restrict__ fb,
                                                   const int* __restrict__ elab,
                                                   float* __restrict__ spos,
                                                   float* __restrict__ sneg) {
    __shared__ __align__(16) char lA[BM * BK * 2];  // 16 KiB
    __shared__ __align__(16) char lB[BM * BK * 2];  // 16 KiB

    const int tid  = threadIdx.x;
    const int lane = tid & 63;
    const int w    = tid >> 6;
    const int wm   = w >> 1, wn = w & 1;
    const int row0 = blockIdx.y * BM;
    const int col0 = blockIdx.x * BM;

    f32x4 acc[4][4] = {};

    const char* fbyte = (const char*)fb;
    const int oBase = w * 1024 + lane * 16;

    for (int ks = 0; ks < KSTEPS; ++ks) {
        const int k0 = ks * BK;
        // ---- stage A and B tiles (linear LDS, pre-swizzled global source) ----
        #pragma unroll
        for (int it = 0; it < 4; ++it) {
            int o   = it * 4096 + oBase;           // linear LDS byte offset
            int r   = o >> 7;                      // tile row
            int cb  = o & 127;                     // col byte within row
            int scb = cb ^ ((r & 7) << 4);         // inverse-swizzled source col
            const char* ga = fbyte + ((size_t)(row0 + r) * DIM + k0) * 2 + scb;
            __builtin_amdgcn_global_load_lds(
                (const __attribute__((address_space(1))) void*)ga,
                (__attribute__((address_space(3))) void*)(lA + it * 4096 + w * 1024),
                16, 0, 0);
            const char* gb = fbyte + ((size_t)(col0 + r) * DIM + k0) * 2 + scb;
            __builtin_amdgcn_global_load_lds(
                (const __attribute__((address_space(1))) void*)gb,
                (__attribute__((address_space(3))) void*)(lB + it * 4096 + w * 1024),
                16, 0, 0);
        }
        asm volatile("s_waitcnt vmcnt(0)");
        __syncthreads();

        // ---- compute: 2 k-halves of 32, 16 MFMA each ----
        #pragma unroll
        for (int kk = 0; kk < 2; ++kk) {
            short8 af[4], bfr[4];
            #pragma unroll
            for (int m = 0; m < 4; ++m) {
                int r  = wm * 64 + m * 16 + (lane & 15);
                int kb = kk * 64 + (lane >> 4) * 16;
                af[m] = *(const short8*)(lA + r * 128 + (kb ^ ((r & 7) << 4)));
            }
            #pragma unroll
            for (int n = 0; n < 4; ++n) {
                int r  = wn * 64 + n * 16 + (lane & 15);
                int kb = kk * 64 + (lane >> 4) * 16;
                bfr[n] = *(const short8*)(lB + r * 128 + (kb ^ ((r & 7) << 4)));
            }
            #pragma unroll
            for (int m = 0; m < 4; ++m)
                #pragma unroll
                for (int n = 0; n < 4; ++n)
                    acc[m][n] = __builtin_amdgcn_mfma_f32_16x16x32_bf16(
                        af[m], bfr[n], acc[m][n], 0, 0, 0);
        }
        __syncthreads();
    }

    // ---- fused epilogue: masked exp + per-row reduce + atomic accumulate ----
    const int c = lane & 15, g = lane >> 4;
    #pragma unroll
    for (int m = 0; m < 4; ++m) {
        #pragma unroll
        for (int rg = 0; rg < 4; ++rg) {
            const int gi = row0 + wm * 64 + m * 16 + g * 4 + rg;
            const int li = elab[gi];
            float pos = 0.0f, neg = 0.0f;
            #pragma unroll
            for (int n = 0; n < 4; ++n) {
                const int gj = col0 + wn * 64 + n * 16 + c;
                const int lj = elab[gj];
                const float s = acc[m][n][rg];
                if (li >= 0 && lj >= 0) {
                    if (li == lj) pos += __expf(-s);
                    else          neg += __expf(s);
                }
            }
            #pragma unroll
            for (int off = 1; off <= 8; off <<= 1) {
                pos += __shfl_xor(pos, off);
                neg += __shfl_xor(neg, off);
            }
            if (c == 0 && li >= 0) {
                atomicAdd(&spos[gi], pos);
                atomicAdd(&sneg[gi], neg);
            }
        }
    }
}

// ---------- finalize: masked mean of log1p(spos*sneg) ----------
__global__ __launch_bounds__(256) void finalize_kernel(const int* __restrict__ elab,
                                                       const float* __restrict__ spos,
                                                       const float* __restrict__ sneg,
                                                       float* __restrict__ accum) {
    int i = blockIdx.x * blockDim.x + threadIdx.x;
    float s = 0.0f, cnt = 0.0f;
    if (i < NTOT && elab[i] >= 0) {
        s = log1pf(spos[i] * sneg[i]);
        cnt = 1.0f;
    }
    #pragma unroll
    for (int off = 1; off < 64; off <<= 1) {
        s   += __shfl_xor(s, off);
        cnt += __shfl_xor(cnt, off);
    }
    __shared__ float sh[8];
    int lane = threadIdx.x & 63, w = threadIdx.x >> 6;
    if (lane == 0) { sh[w] = s; sh[4 + w] = cnt; }
    __syncthreads();
    if (threadIdx.x == 0) {
        atomicAdd(&accum[0], sh[0] + sh[1] + sh[2] + sh[3]);
        atomicAdd(&accum[1], sh[4] + sh[5] + sh[6] + sh[7]);
    }
}

__global__ void writeout_kernel(const float* __restrict__ accum, float* __restrict__ out) {
    out[0] = accum[0] / accum[1];
}

extern "C" void kernel_launch(void* const* d_in, const int* in_sizes, int n_in,
                              void* d_out, int out_size, void* d_ws, size_t ws_size,
                              hipStream_t stream) {
    (void)in_sizes; (void)n_in; (void)out_size; (void)ws_size;
    const float* input_f = (const float*)d_in[0];
    const int*   target  = (const int*)d_in[1];
    float* out = (float*)d_out;

    char* ws = (char*)d_ws;
    const size_t FB_BYTES = (size_t)NTOT * DIM * 2;      // 14,155,776
    __hip_bfloat16* fb = (__hip_bfloat16*)ws;
    int*   elab  = (int*)(ws + FB_BYTES);                // 27,648 B
    float* spos  = (float*)(ws + FB_BYTES + 32768);
    float* sneg  = spos + NTOT;
    float* accum = sneg + NTOT;                          // 2 floats (contiguous after spos/sneg)

    const int nzero = 2 * NTOT + 2;
    zero_kernel<<<dim3((nzero + 255) / 256), dim3(256), 0, stream>>>(spos, nzero);
    prep_kernel<<<dim3(1), dim3(256), 0, stream>>>(target, elab);
    norm_kernel<<<dim3(NTOT), dim3(256), 0, stream>>>(input_f, fb);
    gemm_kernel<<<dim3(NTILES, NTILES), dim3(256), 0, stream>>>(fb, elab, spos, sneg);
    finalize_kernel<<<dim3((NTOT + 255) / 256), dim3(256), 0, stream>>>(elab, spos, sneg, accum);
    writeout_kernel<<<dim3(1), dim3(1), 0, stream>>>(accum, out);
}

// Round 2
// 84.275 us; speedup vs baseline: 2.6907x; 2.6907x over previous
//
#include <hip/hip_runtime.h>
#include <hip/hip_bf16.h>
#include <stdint.h>

#define BATCH 256
#define TSLOT 27
#define NTOT  (BATCH * TSLOT)   // 6912
#define DIM   1024
#define BM    128
#define BK    64
#define NTILES (NTOT / BM)      // 54
#define NTRI  (NTILES * (NTILES + 1) / 2)  // 1485
#define KSTEPS (DIM / BK)       // 16

typedef __attribute__((ext_vector_type(8))) short short8;
typedef __attribute__((ext_vector_type(4))) float f32x4;

// ---------- prep + scan: per-sample valid length, exclusive offsets, totals ----------
// offs[257]: offs[b] = exclusive prefix, offs[256] = nvalid. meta[0]=nvalid, meta[1]=npad.
__global__ __launch_bounds__(256) void prepscan_kernel(const int* __restrict__ tgt,
                                                       int* __restrict__ offs,
                                                       int* __restrict__ meta) {
    int b = threadIdx.x;  // 256 samples
    const int* t = tgt + b * TSLOT;
    int fz = 1;  // argmax over all-False -> 0, +1 => 1
    for (int i = 1; i < TSLOT; ++i) {
        if (t[i] == 0) { fz = i; break; }
    }
    __shared__ int sh[256];
    sh[b] = fz;
    __syncthreads();
    for (int d = 1; d < 256; d <<= 1) {
        int v = (b >= d) ? sh[b - d] : 0;
        __syncthreads();
        sh[b] += v;
        __syncthreads();
    }
    offs[b] = sh[b] - fz;  // exclusive
    if (b == 255) {
        int nv = sh[255];
        offs[256] = nv;
        meta[0] = nv;
        meta[1] = ((nv + 127) / 128) * 128;
    }
}

// ---------- util: zero spos/sneg/accum, clab tail = -1, zero pad rows of cfb ----------
__global__ __launch_bounds__(256) void util_kernel(const int* __restrict__ meta,
                                                   int* __restrict__ clab,
                                                   float* __restrict__ spos,
                                                   float* __restrict__ sneg,
                                                   float* __restrict__ accum,
                                                   __hip_bfloat16* __restrict__ cfb) {
    const int nvalid = meta[0], npad = meta[1];
    const int bid = blockIdx.x, tid = threadIdx.x;
    if (bid < 27) {
        int i = bid * 256 + tid;
        if (i < NTOT) {
            spos[i] = 0.0f;
            sneg[i] = 0.0f;
            int r = nvalid + i;
            if (r < NTOT) clab[r] = -1;
        }
        if (bid == 0 && tid < 2) accum[tid] = 0.0f;
    } else {
        int k = bid - 27;  // 27 blocks x 5 rows >= 128 max pad rows
        for (int j = 0; j < 5; ++j) {
            int r = nvalid + k * 5 + j;
            if (r < npad) {
                float2 z = {0.0f, 0.0f};
                *(float2*)((char*)cfb + (size_t)r * 2048 + tid * 8) = z;
            }
        }
    }
}

// ---------- row L2-normalize f32 -> bf16, scatter to compacted position ----------
__global__ __launch_bounds__(256) void norm_c_kernel(const float* __restrict__ in,
                                                     const int* __restrict__ tgt,
                                                     const int* __restrict__ offs,
                                                     __hip_bfloat16* __restrict__ cfb,
                                                     int* __restrict__ clab) {
    const int r = blockIdx.x;          // source row in [0, NTOT)
    const int b = r / TSLOT, t = r - b * TSLOT;
    const int o0 = offs[b], o1 = offs[b + 1];
    if (t >= o1 - o0) return;          // invalid (padded) slot
    const int dest = o0 + t;
    const int tid = threadIdx.x;
    const float4 v = *(const float4*)(in + (size_t)r * DIM + tid * 4);
    float ss = v.x * v.x + v.y * v.y + v.z * v.z + v.w * v.w;
    #pragma unroll
    for (int off = 1; off < 64; off <<= 1) ss += __shfl_xor(ss, off);
    __shared__ float wsum[4];
    int lane = tid & 63, w = tid >> 6;
    if (lane == 0) wsum[w] = ss;
    __syncthreads();
    float tot = wsum[0] + wsum[1] + wsum[2] + wsum[3];
    float scale = 1.0f / fmaxf(sqrtf(tot), 1e-12f);
    __hip_bfloat16 h0 = __float2bfloat16(v.x * scale);
    __hip_bfloat16 h1 = __float2bfloat16(v.y * scale);
    __hip_bfloat16 h2 = __float2bfloat16(v.z * scale);
    __hip_bfloat16 h3 = __float2bfloat16(v.w * scale);
    ushort4 o;
    o.x = *(unsigned short*)&h0;
    o.y = *(unsigned short*)&h1;
    o.z = *(unsigned short*)&h2;
    o.w = *(unsigned short*)&h3;
    *(ushort4*)((unsigned short*)cfb + (size_t)dest * DIM + tid * 4) = o;
    if (tid == 0) clab[dest] = tgt[r];
}

// ---------- symmetric fused GEMM (upper-tri blocks) + masked exp accumulation ----------
__global__ __launch_bounds__(256) void gemm_kernel(const __hip_bfloat16* __restrict__ fb,
                                                   const int* __restrict__ clab,
                                                   const int* __restrict__ meta,
                                                   float* __restrict__ spos,
                                                   float* __restrict__ sneg) {
    __shared__ __align__(16) char lA[BM * BK * 2];  // 16 KiB
    __shared__ __align__(16) char lB[BM * BK * 2];  // 16 KiB

    // unrank upper-triangular block index (row-major incl. diagonal)
    int t = blockIdx.x, bi = 0;
    while (t >= NTILES - bi) { t -= NTILES - bi; ++bi; }
    const int bj = bi + t;
    const int npad = meta[1];
    const int col0 = bj * BM;
    if (col0 >= npad) return;          // beyond compacted range (bi<=bj => row0 ok too)
    const int row0 = bi * BM;
    const bool diag = (bi == bj);

    const int tid  = threadIdx.x;
    const int lane = tid & 63;
    const int w    = tid >> 6;
    const int wm   = w >> 1, wn = w & 1;

    f32x4 acc[4][4] = {};

    const char* fbyte = (const char*)fb;
    const int oBase = w * 1024 + lane * 16;
    const char* lBp = diag ? lA : lB;

    for (int ks = 0; ks < KSTEPS; ++ks) {
        const int k0 = ks * BK;
        #pragma unroll
        for (int it = 0; it < 4; ++it) {
            int o   = it * 4096 + oBase;           // linear LDS byte offset
            int r   = o >> 7;                      // tile row
            int cb  = o & 127;                     // col byte within row
            int scb = cb ^ ((r & 7) << 4);         // inverse-swizzled source col
            const char* ga = fbyte + ((size_t)(row0 + r) * DIM + k0) * 2 + scb;
            __builtin_amdgcn_global_load_lds(
                (const __attribute__((address_space(1))) void*)ga,
                (__attribute__((address_space(3))) void*)(lA + it * 4096 + w * 1024),
                16, 0, 0);
            if (!diag) {
                const char* gb = fbyte + ((size_t)(col0 + r) * DIM + k0) * 2 + scb;
                __builtin_amdgcn_global_load_lds(
                    (const __attribute__((address_space(1))) void*)gb,
                    (__attribute__((address_space(3))) void*)(lB + it * 4096 + w * 1024),
                    16, 0, 0);
            }
        }
        asm volatile("s_waitcnt vmcnt(0)");
        __syncthreads();

        #pragma unroll
        for (int kk = 0; kk < 2; ++kk) {
            short8 af[4], bfr[4];
            #pragma unroll
            for (int m = 0; m < 4; ++m) {
                int r  = wm * 64 + m * 16 + (lane & 15);
                int kb = kk * 64 + (lane >> 4) * 16;
                af[m] = *(const short8*)(lA + r * 128 + (kb ^ ((r & 7) << 4)));
            }
            #pragma unroll
            for (int n = 0; n < 4; ++n) {
                int r  = wn * 64 + n * 16 + (lane & 15);
                int kb = kk * 64 + (lane >> 4) * 16;
                bfr[n] = *(const short8*)(lBp + r * 128 + (kb ^ ((r & 7) << 4)));
            }
            #pragma unroll
            for (int m = 0; m < 4; ++m)
                #pragma unroll
                for (int n = 0; n < 4; ++n)
                    acc[m][n] = __builtin_amdgcn_mfma_f32_16x16x32_bf16(
                        af[m], bfr[n], acc[m][n], 0, 0, 0);
        }
        __syncthreads();
    }

    // ---- fused epilogue ----
    // C/D layout: col = lane&15, row = (lane>>4)*4 + reg
    const int c = lane & 15, g = lane >> 4;
    float cpos[4] = {0, 0, 0, 0}, cneg[4] = {0, 0, 0, 0};

    #pragma unroll
    for (int m = 0; m < 4; ++m) {
        #pragma unroll
        for (int rg = 0; rg < 4; ++rg) {
            const int gi = row0 + wm * 64 + m * 16 + g * 4 + rg;
            const int li = clab[gi];
            float rp = 0.0f, rn = 0.0f;
            #pragma unroll
            for (int n = 0; n < 4; ++n) {
                const int gj = col0 + wn * 64 + n * 16 + c;
                const int lj = clab[gj];
                const float s = acc[m][n][rg];
                if (li >= 0 && lj >= 0) {
                    if (li == lj) { float e = __expf(-s); rp += e; cpos[n] += e; }
                    else          { float e = __expf(s);  rn += e; cneg[n] += e; }
                }
            }
            #pragma unroll
            for (int off = 1; off <= 8; off <<= 1) {
                rp += __shfl_xor(rp, off);
                rn += __shfl_xor(rn, off);
            }
            if (c == 0 && li >= 0) {
                atomicAdd(&spos[gi], rp);
                atomicAdd(&sneg[gi], rn);
            }
        }
    }

    if (!diag) {
        // column credit: reduce over g groups (rows), lanes g==0 write 16 cols
        #pragma unroll
        for (int n = 0; n < 4; ++n) {
            float p = cpos[n], q = cneg[n];
            p += __shfl_xor(p, 16); p += __shfl_xor(p, 32);
            q += __shfl_xor(q, 16); q += __shfl_xor(q, 32);
            const int gj = col0 + wn * 64 + n * 16 + c;
            const int lj = clab[gj];
            if (g == 0 && lj >= 0) {
                atomicAdd(&spos[gj], p);
                atomicAdd(&sneg[gj], q);
            }
        }
    }
}

// ---------- finalize: masked mean of log1p(spos*sneg) ----------
__global__ __launch_bounds__(256) void finalize_kernel(const int* __restrict__ clab,
                                                       const float* __restrict__ spos,
                                                       const float* __restrict__ sneg,
                                                       float* __restrict__ accum) {
    int i = blockIdx.x * blockDim.x + threadIdx.x;
    float s = 0.0f, cnt = 0.0f;
    if (i < NTOT && clab[i] >= 0) {
        s = log1pf(spos[i] * sneg[i]);
        cnt = 1.0f;
    }
    #pragma unroll
    for (int off = 1; off < 64; off <<= 1) {
        s   += __shfl_xor(s, off);
        cnt += __shfl_xor(cnt, off);
    }
    __shared__ float sh[8];
    int lane = threadIdx.x & 63, w = threadIdx.x >> 6;
    if (lane == 0) { sh[w] = s; sh[4 + w] = cnt; }
    __syncthreads();
    if (threadIdx.x == 0) {
        atomicAdd(&accum[0], sh[0] + sh[1] + sh[2] + sh[3]);
        atomicAdd(&accum[1], sh[4] + sh[5] + sh[6] + sh[7]);
    }
}

__global__ void writeout_kernel(const float* __restrict__ accum, float* __restrict__ out) {
    out[0] = accum[0] / accum[1];
}

extern "C" void kernel_launch(void* const* d_in, const int* in_sizes, int n_in,
                              void* d_out, int out_size, void* d_ws, size_t ws_size,
                              hipStream_t stream) {
    (void)in_sizes; (void)n_in; (void)out_size; (void)ws_size;
    const float* input_f = (const float*)d_in[0];
    const int*   target  = (const int*)d_in[1];
    float* out = (float*)d_out;

    char* ws = (char*)d_ws;
    const size_t FB_BYTES = (size_t)NTOT * DIM * 2;      // 14,155,776
    __hip_bfloat16* cfb = (__hip_bfloat16*)ws;
    char* p = ws + FB_BYTES;
    int*   clab  = (int*)p;            p += NTOT * 4;    // 27,648
    int*   offs  = (int*)p;            p += 4096;        // 257 ints, padded
    int*   meta  = (int*)p;            p += 256;
    float* spos  = (float*)p;          p += NTOT * 4;
    float* sneg  = (float*)p;          p += NTOT * 4;
    float* accum = (float*)p;

    prepscan_kernel<<<dim3(1), dim3(256), 0, stream>>>(target, offs, meta);
    util_kernel<<<dim3(54), dim3(256), 0, stream>>>(meta, clab, spos, sneg, accum, cfb);
    norm_c_kernel<<<dim3(NTOT), dim3(256), 0, stream>>>(input_f, target, offs, cfb, clab);
    gemm_kernel<<<dim3(NTRI), dim3(256), 0, stream>>>(cfb, clab, meta, spos, sneg);
    finalize_kernel<<<dim3((NTOT + 255) / 256), dim3(256), 0, stream>>>(clab, spos, sneg, accum);
    writeout_kernel<<<dim3(1), dim3(1), 0, stream>>>(accum, out);
}